// Round 7
// baseline (239.259 us; speedup 1.0000x reference)
//
#include <hip/hip_runtime.h>

#define KC 1024   // codes
#define DD 128    // dim
#define NT_COUNT (KC / 16)   // 64 code-tiles of 16
#define RPB 128   // rows per block (4 waves x 32 rows)

typedef short bf16x8 __attribute__((ext_vector_type(8)));
typedef float f32x4  __attribute__((ext_vector_type(4)));

#define AS1 __attribute__((address_space(1)))
#define AS3 __attribute__((address_space(3)))

static __device__ __forceinline__ unsigned short f2bf(float f) {
    unsigned u = __float_as_uint(f);
    unsigned r = (u + 0x7fffu + ((u >> 16) & 1u)) >> 16;   // RNE
    return (unsigned short)r;
}
static __device__ __forceinline__ float bf2f(unsigned short h) {
    return __uint_as_float(((unsigned)h) << 16);
}
static __device__ __forceinline__ void gl_lds16(const void* g, void* l) {
    __builtin_amdgcn_global_load_lds((const AS1 void*)g, (AS3 void*)l, 16, 0, 0);
}

// ---------------- fused prep: e2h (+512 offset) + ET + packed bf16 hi/lo B-fragments ----------------
// Bpk byte layout: [nt][c(8)x1024][lane(64)x16]; c<4 = hi s=c, c>=4 = lo s=c-4.
//   element (d,k): d = s*32 + (lane>>4)*8 + j ; k = nt*16 + (lane&15)
__global__ __launch_bounds__(256) void vq_prep(const float* __restrict__ E,
                                               float* __restrict__ e2h,
                                               float* __restrict__ ET,
                                               unsigned short* __restrict__ Bpk) {
    __shared__ float T[16 * 129];   // [k][d]
    const int nt  = blockIdx.x;     // 64 blocks, 16 codes each
    const int tid = threadIdx.x;

    for (int i = tid; i < 16 * DD; i += 256) {
        int d  = i >> 4;
        int kk = i & 15;
        T[kk * 129 + d] = E[(size_t)d * KC + nt * 16 + kk];
    }
    __syncthreads();

    // e2h = 512 - 0.5*||e_k||^2 (offset keeps all screen scores positive, < 512)
    if (tid < 16) {
        float s = 0.f;
#pragma unroll 16
        for (int d = 0; d < DD; ++d) {
            float v = T[tid * 129 + d];
            s = fmaf(v, v, s);
        }
        e2h[nt * 16 + tid] = 512.0f - 0.5f * s;
    }

    for (int i = tid; i < 16 * DD; i += 256) {
        int kk = i >> 7;
        int d  = i & 127;
        ET[(size_t)(nt * 16 + kk) * DD + d] = T[kk * 129 + d];
    }

    {
        const int s    = tid >> 6;
        const int lane = tid & 63;
        const int kk   = lane & 15;
        const int d0   = s * 32 + (lane >> 4) * 8;
        bf16x8 hi, lo;
#pragma unroll
        for (int j = 0; j < 8; ++j) {
            float v = T[kk * 129 + d0 + j];
            unsigned short h = f2bf(v);
            hi[j] = (short)h;
            lo[j] = (short)f2bf(v - bf2f(h));
        }
        char* base = (char*)Bpk + (size_t)nt * 8192 + s * 1024 + lane * 16;
        *(bf16x8*)(base)        = hi;
        *(bf16x8*)(base + 4096) = lo;
    }
}

// ---------------- main: 4-wave blocks share LDS B-tile; raw-barrier depth-1 pipeline ----------------
// LDS: [0,16384) B dbuf | [16384,20480) e2 table | [20480+) epilogue arrays.
__global__ __launch_bounds__(256, 4) void vq_main(const float* __restrict__ X,
                                                  const float* __restrict__ e2h,
                                                  const float* __restrict__ ET,
                                                  const unsigned short* __restrict__ Bpk,
                                                  float* __restrict__ Out) {
    __shared__ __align__(16) char lds[24064];
    float*  e2s   = (float*)(lds + 16384);    // [1024]
    int*    s_k1  = (int*)(lds + 20480);      // [128]
    int*    s_k2  = (int*)(lds + 20992);      // [128]
    int*    s_win = (int*)(lds + 21504);      // [128]
    double* s_d   = (double*)(lds + 22016);   // [256]

    const int tid   = threadIdx.x;
    const int wave  = tid >> 6;
    const int lane  = tid & 63;
    const int quad  = lane >> 4;
    const int n16   = lane & 15;
    const int brow0 = blockIdx.x * RPB;
    const int wrow0 = brow0 + wave * 32;
    const int lidx16 = lane * 16;
    const int wave2  = wave * 2;              // this wave stages fragments {2w, 2w+1}
    const int phase  = blockIdx.x & 63;       // stagger the Bpk stream across blocks

    // ---- e2 table into LDS once (kills the per-tile 64B global hotspot)
    for (int i = tid; i < KC; i += 256) e2s[i] = e2h[i];

    // ---- A-fragments: 2 m-tiles x 4 k-steps, hi+lo (64 VGPRs)
    bf16x8 ahi[2][4], alo[2][4];
#pragma unroll
    for (int t = 0; t < 2; ++t) {
#pragma unroll
        for (int s = 0; s < 4; ++s) {
            const int row = wrow0 + t * 16 + n16;
            const int d0  = s * 32 + quad * 8;
            const float4 p = *(const float4*)(X + (size_t)row * DD + d0);
            const float4 q = *(const float4*)(X + (size_t)row * DD + d0 + 4);
            float v[8] = {p.x, p.y, p.z, p.w, q.x, q.y, q.z, q.w};
#pragma unroll
            for (int j = 0; j < 8; ++j) {
                unsigned short h = f2bf(v[j]);
                ahi[t][s][j] = (short)h;
                alo[t][s][j] = (short)f2bf(v[j] - bf2f(h));
            }
        }
    }

    // ---- top-2 trackers: positive floats with 6-bit physical-tile id in low mantissa
    float p1[2][4], p2[2][4];
#pragma unroll
    for (int t = 0; t < 2; ++t)
#pragma unroll
        for (int r = 0; r < 4; ++r) { p1[t][r] = 0.0f; p2[t][r] = 0.0f; }

#define STAGE(NTP, BOFF)                                                         \
    do {                                                                         \
        const char* g = (const char*)Bpk + (size_t)(NTP) * 8192                  \
                        + wave2 * 1024 + lidx16;                                 \
        gl_lds16(g,        lds + (BOFF) + wave2 * 1024);                         \
        gl_lds16(g + 1024, lds + (BOFF) + wave2 * 1024 + 1024);                  \
    } while (0)

#define TILE(NTP, BOFF)                                                          \
    do {                                                                         \
        const char* l = lds + (BOFF);                                            \
        const float ev = e2s[(NTP) * 16 + n16];                                  \
        const bf16x8 bh0 = *(const bf16x8*)(l + 0 * 1024 + lidx16);              \
        const bf16x8 bh1 = *(const bf16x8*)(l + 1 * 1024 + lidx16);              \
        const bf16x8 bh2 = *(const bf16x8*)(l + 2 * 1024 + lidx16);              \
        const bf16x8 bh3 = *(const bf16x8*)(l + 3 * 1024 + lidx16);              \
        f32x4 acc0 = {ev, ev, ev, ev};                                           \
        f32x4 acc1 = {ev, ev, ev, ev};                                           \
        acc0 = __builtin_amdgcn_mfma_f32_16x16x32_bf16(ahi[0][0], bh0, acc0, 0, 0, 0); \
        acc1 = __builtin_amdgcn_mfma_f32_16x16x32_bf16(ahi[1][0], bh0, acc1, 0, 0, 0); \
        acc0 = __builtin_amdgcn_mfma_f32_16x16x32_bf16(ahi[0][1], bh1, acc0, 0, 0, 0); \
        acc1 = __builtin_amdgcn_mfma_f32_16x16x32_bf16(ahi[1][1], bh1, acc1, 0, 0, 0); \
        acc0 = __builtin_amdgcn_mfma_f32_16x16x32_bf16(ahi[0][2], bh2, acc0, 0, 0, 0); \
        acc1 = __builtin_amdgcn_mfma_f32_16x16x32_bf16(ahi[1][2], bh2, acc1, 0, 0, 0); \
        acc0 = __builtin_amdgcn_mfma_f32_16x16x32_bf16(ahi[0][3], bh3, acc0, 0, 0, 0); \
        acc1 = __builtin_amdgcn_mfma_f32_16x16x32_bf16(ahi[1][3], bh3, acc1, 0, 0, 0); \
        acc0 = __builtin_amdgcn_mfma_f32_16x16x32_bf16(alo[0][0], bh0, acc0, 0, 0, 0); \
        acc1 = __builtin_amdgcn_mfma_f32_16x16x32_bf16(alo[1][0], bh0, acc1, 0, 0, 0); \
        acc0 = __builtin_amdgcn_mfma_f32_16x16x32_bf16(alo[0][1], bh1, acc0, 0, 0, 0); \
        acc1 = __builtin_amdgcn_mfma_f32_16x16x32_bf16(alo[1][1], bh1, acc1, 0, 0, 0); \
        acc0 = __builtin_amdgcn_mfma_f32_16x16x32_bf16(alo[0][2], bh2, acc0, 0, 0, 0); \
        acc1 = __builtin_amdgcn_mfma_f32_16x16x32_bf16(alo[1][2], bh2, acc1, 0, 0, 0); \
        acc0 = __builtin_amdgcn_mfma_f32_16x16x32_bf16(alo[0][3], bh3, acc0, 0, 0, 0); \
        acc1 = __builtin_amdgcn_mfma_f32_16x16x32_bf16(alo[1][3], bh3, acc1, 0, 0, 0); \
        const bf16x8 bl0 = *(const bf16x8*)(l + 4 * 1024 + lidx16);              \
        const bf16x8 bl1 = *(const bf16x8*)(l + 5 * 1024 + lidx16);              \
        const bf16x8 bl2 = *(const bf16x8*)(l + 6 * 1024 + lidx16);              \
        const bf16x8 bl3 = *(const bf16x8*)(l + 7 * 1024 + lidx16);              \
        acc0 = __builtin_amdgcn_mfma_f32_16x16x32_bf16(ahi[0][0], bl0, acc0, 0, 0, 0); \
        acc1 = __builtin_amdgcn_mfma_f32_16x16x32_bf16(ahi[1][0], bl0, acc1, 0, 0, 0); \
        acc0 = __builtin_amdgcn_mfma_f32_16x16x32_bf16(ahi[0][1], bl1, acc0, 0, 0, 0); \
        acc1 = __builtin_amdgcn_mfma_f32_16x16x32_bf16(ahi[1][1], bl1, acc1, 0, 0, 0); \
        acc0 = __builtin_amdgcn_mfma_f32_16x16x32_bf16(ahi[0][2], bl2, acc0, 0, 0, 0); \
        acc1 = __builtin_amdgcn_mfma_f32_16x16x32_bf16(ahi[1][2], bl2, acc1, 0, 0, 0); \
        acc0 = __builtin_amdgcn_mfma_f32_16x16x32_bf16(ahi[0][3], bl3, acc0, 0, 0, 0); \
        acc1 = __builtin_amdgcn_mfma_f32_16x16x32_bf16(ahi[1][3], bl3, acc1, 0, 0, 0); \
        const unsigned ntinv = (unsigned)(63 - (NTP));                           \
        _Pragma("unroll")                                                        \
        for (int r = 0; r < 4; ++r) {                                            \
            float v0 = __uint_as_float((__float_as_uint(acc0[r]) & ~63u) | ntinv); \
            float l0 = fminf(p1[0][r], v0);                                      \
            p1[0][r] = fmaxf(p1[0][r], v0);                                      \
            p2[0][r] = fmaxf(p2[0][r], l0);                                      \
            float v1 = __uint_as_float((__float_as_uint(acc1[r]) & ~63u) | ntinv); \
            float l1 = fminf(p1[1][r], v1);                                      \
            p1[1][r] = fmaxf(p1[1][r], v1);                                      \
            p2[1][r] = fmaxf(p2[1][r], l1);                                      \
        }                                                                        \
    } while (0)

    STAGE(phase, 0);
    __syncthreads();   // one full drain: e2s + tile-0 fragments ready for all waves

    for (int it = 0; it < NT_COUNT; ++it) {
        const int boff = (it & 1) ? 8192 : 0;
        if (it + 1 < NT_COUNT) {
            STAGE((phase + it + 1) & 63, boff ^ 8192);   // issue next tile early
        }
        TILE((phase + it) & 63, boff);                   // ~900 cyc of MFMA hides the loads
        if (it + 1 < NT_COUNT) {
            __builtin_amdgcn_s_waitcnt(3952);            // vmcnt(0): own 2 loads landed
            __builtin_amdgcn_sched_barrier(0);
            __builtin_amdgcn_s_barrier();                // raw barrier — no lgkm/vm drain
            __builtin_amdgcn_sched_barrier(0);
        }
    }
#undef STAGE
#undef TILE

    // ---- re-attach full k, merge top-2 across the 16 n-lanes (u64 butterfly)
#pragma unroll
    for (int t = 0; t < 2; ++t) {
#pragma unroll
        for (int r = 0; r < 4; ++r) {
            unsigned u1 = __float_as_uint(p1[t][r]);
            unsigned u2 = __float_as_uint(p2[t][r]);
            int k1 = (int)(63u - (u1 & 63u)) * 16 + n16;
            int k2 = (int)(63u - (u2 & 63u)) * 16 + n16;
            unsigned long long q1 =
                ((unsigned long long)(u1 & ~63u) << 32) | (unsigned)(1023 - k1);
            unsigned long long q2 =
                ((unsigned long long)(u2 & ~63u) << 32) | (unsigned)(1023 - k2);
#pragma unroll
            for (int m = 1; m < 16; m <<= 1) {
                unsigned long long o1 = __shfl_xor(q1, m, 64);
                unsigned long long o2 = __shfl_xor(q2, m, 64);
                unsigned long long lo = q1 < o1 ? q1 : o1;
                q1 = q1 > o1 ? q1 : o1;
                unsigned long long hi2 = q2 > o2 ? q2 : o2;
                q2 = lo > hi2 ? lo : hi2;
            }
            if (n16 == 0) {
                int row = wave * 32 + t * 16 + quad * 4 + r;
                s_k1[row] = 1023 - (int)(q1 & 1023u);
                s_k2[row] = 1023 - (int)(q2 & 1023u);
            }
        }
    }
    __syncthreads();

    // ---- fp64 rescore: 128 rows x 2 candidates (dist = e^2 - 2 x.e; x^2 constant/row)
    {
        const int row = tid >> 1;
        const int k   = (tid & 1) ? s_k2[row] : s_k1[row];
        const float* __restrict__ xrow = X + (size_t)(brow0 + row) * DD;
        const float* __restrict__ erow = ET + (size_t)k * DD;
        double dot = 0.0, ee = 0.0;
#pragma unroll 8
        for (int d = 0; d < DD; ++d) {
            double xv = (double)xrow[d];
            double evd = (double)erow[d];
            dot = fma(xv, evd, dot);
            ee  = fma(evd, evd, ee);
        }
        s_d[tid] = ee - 2.0 * dot;
    }
    __syncthreads();
    if (tid < RPB) {
        double d1 = s_d[2 * tid];
        double d2 = s_d[2 * tid + 1];
        int kk1 = s_k1[tid], kk2 = s_k2[tid];
        s_win[tid] = (d2 < d1 || (d2 == d1 && kk2 < kk1)) ? kk2 : kk1;
    }
    __syncthreads();

    // ---- gather winning code rows (exact fp32 copies), coalesced float4
    for (int i = tid; i < RPB * (DD / 4); i += 256) {
        const int row = i >> 5;
        const int d4  = i & 31;
        const float4 v = *(const float4*)(ET + (size_t)s_win[row] * DD + d4 * 4);
        *(float4*)(Out + (size_t)(brow0 + row) * DD + d4 * 4) = v;
    }
}

extern "C" void kernel_launch(void* const* d_in, const int* in_sizes, int n_in,
                              void* d_out, int out_size, void* d_ws, size_t ws_size,
                              hipStream_t stream) {
    const float* X = (const float*)d_in[0];   // [131072, 128]
    const float* E = (const float*)d_in[1];   // [128, 1024]
    float* Out = (float*)d_out;

    // workspace: e2h (4 KB) | ET (512 KB) | Bpk (512 KB)
    float* e2h = (float*)d_ws;
    float* ET  = e2h + KC;
    unsigned short* Bpk = (unsigned short*)(ET + (size_t)KC * DD);

    const int N = in_sizes[0] / DD;   // 131072

    hipLaunchKernelGGL(vq_prep, dim3(NT_COUNT), dim3(256), 0, stream, E, e2h, ET, Bpk);
    hipLaunchKernelGGL(vq_main, dim3(N / RPB), dim3(256), 0, stream,
                       X, e2h, ET, Bpk, Out);
}